// Round 1
// baseline (372.814 us; speedup 1.0000x reference)
//
#include <hip/hip_runtime.h>
#include <math.h>

#define NN 2048
#define BATCH 32
#define COLS 64            // 32 sin cols + 32 cos cols
#define DT_STEP 0.1f
#define NSTEPS 10

// ---------------------------------------------------------------------------
// init: copy theta0 into d_out's theta region, build X[j][col]:
//   X[j][b]      = sin(theta[b][j])
//   X[j][32 + b] = cos(theta[b][j])
// ---------------------------------------------------------------------------
__global__ __launch_bounds__(256) void init_kernel(const float* __restrict__ theta_in,
                                                   float* __restrict__ theta,
                                                   float* __restrict__ X) {
    int t = blockIdx.x * 256 + threadIdx.x;      // t = b*NN + i
    int b = t >> 11;
    int i = t & (NN - 1);
    float th = theta_in[t];
    theta[t] = th;
    X[(size_t)i * COLS + b]      = sinf(th);
    X[(size_t)i * COLS + 32 + b] = cosf(th);
}

// ---------------------------------------------------------------------------
// gemm: partial[split][i][col] = sum_{j in split} K[i][j] * X[j][col]
// block: 256 threads -> 64 rows x 64 cols tile; thread: 4 rows x 4 cols.
// grid: (32 row-blocks, JSPLIT splits)
// ---------------------------------------------------------------------------
#define FMA4(A, S, V)                      \
    A.x = fmaf(S, V.x, A.x);               \
    A.y = fmaf(S, V.y, A.y);               \
    A.z = fmaf(S, V.z, A.z);               \
    A.w = fmaf(S, V.w, A.w);

__global__ __launch_bounds__(256) void gemm_kernel(const float* __restrict__ K,
                                                   const float* __restrict__ X,
                                                   float* __restrict__ partial,
                                                   int jrange) {
    const int tid = threadIdx.x;
    const int cg  = tid & 15;        // 16 col groups of 4
    const int rg  = tid >> 4;        // 16 row groups of 4
    const int c0  = cg * 4;
    const int rowBase = blockIdx.x * 64 + rg * 4;
    const int j0 = blockIdx.y * jrange;

    const float* Kp = K + (size_t)rowBase * NN + j0;
    const float* Xp = X + (size_t)j0 * COLS + c0;

    float4 acc0 = {0.f, 0.f, 0.f, 0.f};
    float4 acc1 = {0.f, 0.f, 0.f, 0.f};
    float4 acc2 = {0.f, 0.f, 0.f, 0.f};
    float4 acc3 = {0.f, 0.f, 0.f, 0.f};

    for (int j = 0; j < jrange; j += 4) {
        float4 xv0 = *(const float4*)(Xp + (size_t)(j + 0) * COLS);
        float4 xv1 = *(const float4*)(Xp + (size_t)(j + 1) * COLS);
        float4 xv2 = *(const float4*)(Xp + (size_t)(j + 2) * COLS);
        float4 xv3 = *(const float4*)(Xp + (size_t)(j + 3) * COLS);
        float4 k0 = *(const float4*)(Kp + 0 * NN + j);
        float4 k1 = *(const float4*)(Kp + 1 * NN + j);
        float4 k2 = *(const float4*)(Kp + 2 * NN + j);
        float4 k3 = *(const float4*)(Kp + 3 * NN + j);

        FMA4(acc0, k0.x, xv0) FMA4(acc0, k0.y, xv1) FMA4(acc0, k0.z, xv2) FMA4(acc0, k0.w, xv3)
        FMA4(acc1, k1.x, xv0) FMA4(acc1, k1.y, xv1) FMA4(acc1, k1.z, xv2) FMA4(acc1, k1.w, xv3)
        FMA4(acc2, k2.x, xv0) FMA4(acc2, k2.y, xv1) FMA4(acc2, k2.z, xv2) FMA4(acc2, k2.w, xv3)
        FMA4(acc3, k3.x, xv0) FMA4(acc3, k3.y, xv1) FMA4(acc3, k3.z, xv2) FMA4(acc3, k3.w, xv3)
    }

    float* pp = partial + (size_t)blockIdx.y * (NN * COLS)
                        + (size_t)rowBase * COLS + c0;
    *(float4*)(pp + 0 * COLS) = acc0;
    *(float4*)(pp + 1 * COLS) = acc1;
    *(float4*)(pp + 2 * COLS) = acc2;
    *(float4*)(pp + 3 * COLS) = acc3;
}

// ---------------------------------------------------------------------------
// update: sum split partials, apply Kuramoto step, wrap, refresh X.
// thread t = b*NN + i (coalesced on theta layout [b][i])
// ---------------------------------------------------------------------------
__global__ __launch_bounds__(256) void update_kernel(float* __restrict__ theta,
                                                     float* __restrict__ X,
                                                     const float* __restrict__ partial,
                                                     const float* __restrict__ omega,
                                                     const float* __restrict__ Kg,
                                                     const float* __restrict__ mu,
                                                     int js) {
    int t = blockIdx.x * 256 + threadIdx.x;
    int b = t >> 11;
    int i = t & (NN - 1);

    float sumS = 0.f, sumC = 0.f;
    for (int s = 0; s < js; ++s) {
        const float* p = partial + (size_t)s * (NN * COLS) + (size_t)i * COLS;
        sumS += p[b];
        sumC += p[32 + b];
    }

    float g = (Kg[0] / (float)NN) * (mu[0] * 0.5f);   // coef * mu-branch scale
    float sV = X[(size_t)i * COLS + b];        // sin(theta[b][i])
    float cV = X[(size_t)i * COLS + 32 + b];   // cos(theta[b][i])
    float th = theta[t];

    float dth = omega[i] + g * (cV * sumS - sV * sumC);
    float thn = th + DT_STEP * dth;
    float s = sinf(thn);
    float c = cosf(thn);
    theta[t] = atan2f(s, c);                   // wrap to (-pi, pi]
    X[(size_t)i * COLS + b]      = s;          // sin is 2pi-periodic: sin(wrapped)=s
    X[(size_t)i * COLS + 32 + b] = c;
}

// ---------------------------------------------------------------------------
// coherence: per batch b, sqrt(mean(cos th)^2 + mean(sin th)^2)
// ---------------------------------------------------------------------------
__global__ __launch_bounds__(256) void coh_kernel(const float* __restrict__ theta,
                                                  float* __restrict__ out) {
    int b = blockIdx.x;
    const float* th = theta + (size_t)b * NN;
    float sc = 0.f, ss = 0.f;
    for (int i = threadIdx.x; i < NN; i += 256) {
        float t = th[i];
        sc += cosf(t);
        ss += sinf(t);
    }
    // wave reduce (64 lanes)
    for (int off = 32; off > 0; off >>= 1) {
        sc += __shfl_down(sc, off);
        ss += __shfl_down(ss, off);
    }
    __shared__ float red[2][4];
    int wave = threadIdx.x >> 6;
    if ((threadIdx.x & 63) == 0) { red[0][wave] = sc; red[1][wave] = ss; }
    __syncthreads();
    if (threadIdx.x == 0) {
        float csum = red[0][0] + red[0][1] + red[0][2] + red[0][3];
        float ssum = red[1][0] + red[1][1] + red[1][2] + red[1][3];
        float cm = csum / (float)NN;
        float sm = ssum / (float)NN;
        out[b] = sqrtf(cm * cm + sm * sm);
    }
}

extern "C" void kernel_launch(void* const* d_in, const int* in_sizes, int n_in,
                              void* d_out, int out_size, void* d_ws, size_t ws_size,
                              hipStream_t stream) {
    const float* theta0 = (const float*)d_in[0];
    const float* K      = (const float*)d_in[1];
    const float* omega  = (const float*)d_in[2];
    const float* Kg     = (const float*)d_in[3];
    const float* mu     = (const float*)d_in[4];

    float* out   = (float*)d_out;
    float* theta = out;                 // first BATCH*NN elements
    float* coh   = out + BATCH * NN;    // last BATCH elements

    float* X = (float*)d_ws;            // NN x COLS
    size_t per = (size_t)NN * COLS * sizeof(float);   // 512 KB
    int js = 16;
    while (js > 1 && (per + (size_t)js * per) > ws_size) js >>= 1;
    float* partial = (float*)((char*)d_ws + per);
    int jrange = NN / js;

    int nelem_blocks = (BATCH * NN) / 256;

    init_kernel<<<nelem_blocks, 256, 0, stream>>>(theta0, theta, X);
    for (int step = 0; step < NSTEPS; ++step) {
        gemm_kernel<<<dim3(32, js), 256, 0, stream>>>(K, X, partial, jrange);
        update_kernel<<<nelem_blocks, 256, 0, stream>>>(theta, X, partial, omega, Kg, mu, js);
    }
    coh_kernel<<<BATCH, 256, 0, stream>>>(theta, coh);
}